// Round 10
// baseline (149.914 us; speedup 1.0000x reference)
//
#include <hip/hip_runtime.h>

// x:(8,32,32,64,64) f32 -> out:(8,32,48,96,96) f32
// variance=1: out = 2*log( trilinear( exp(x/2) ) ), identity grid, align_corners=True.
//
// R9's trimmed 3-phase structure + persistent-over-4-planes pipeline:
//  Block = 4 consecutive zo of one nc. Per plane:
//   STAGE: regs -> G[64][68] (exp + z-combine)          [loads issued a full plane ago]
//   issue next plane's 8 dwordx4 loads into regs        [latency hides under phases 2-3]
//   2x { phase2: G->F2[48][68] y-lerp (float4 DS ops); phase3: 1152 quads x-lerp+2log }
//  Consecutive zo reuse z-planes within the SAME CU (L1/L2-local, ~2.6x less read traffic).
constexpr int N = 8, C = 32, Din = 32, Hin = 64, Win = 64;
constexpr int Do = 48, Ho = 96, Wo = 96;

constexpr int BLOCK   = 256;
constexpr int PPB     = 4;                    // planes (zo) per block; 48 % 4 == 0
constexpr int NBLOCKS = N * C * Do / PPB;     // 3072
constexpr int GPAD    = 68;
constexpr int F2PAD   = 68;
constexpr int HROWS   = 48;
constexpr int QUADS   = HROWS * (Wo / 4);     // 1152 per half

typedef float f32x4 __attribute__((ext_vector_type(4)));

__global__ __launch_bounds__(BLOCK, 4)
void resample3d_var_kernel(const float* __restrict__ in, float* __restrict__ out) {
    __shared__ float G[Hin][GPAD];            // 17408 B
    __shared__ float F2[HROWS][F2PAD];        // 13056 B

    const int tid    = threadIdx.x;
    const int plane0 = blockIdx.x * PPB;      // = nc*Do + zo0, zo-run stays inside nc
    const int nc     = plane0 / Do;
    const int zo0    = plane0 % Do;

    const float* __restrict__ base = in + (size_t)nc * (Din * Hin * Win);

    constexpr float HALF_LOG2E = 0.7213475204444817f;   // exp(x/2)  = exp2(x*K)
    constexpr float TWO_LN2    = 1.3862943611198906f;   // 2*logf(v) = TWO_LN2*log2f(v)

    const int sy = tid >> 4;                  // 0..15
    const int sx = (tid & 15) << 2;           // 0,4,...,60

    f32x4 ra[4], rb[4];                       // prefetch registers (static-indexed only)

#define ISSUE_LOADS(zovar)                                               \
    {                                                                    \
        int   zz  = (zovar);                                             \
        float fzl = (float)(zz * (Din - 1)) * (1.0f / (float)(Do - 1));  \
        int   z0l = (int)fzl;                                            \
        int   z1l = min(z0l + 1, Din - 1);                               \
        const float* __restrict__ p0 = base + (size_t)z0l * (Hin * Win); \
        const float* __restrict__ p1 = base + (size_t)z1l * (Hin * Win); \
        _Pragma("unroll")                                                \
        for (int k = 0; k < 4; ++k) {                                    \
            int y = sy + k * 16;                                         \
            ra[k] = *reinterpret_cast<const f32x4*>(p0 + y * Win + sx);  \
            rb[k] = *reinterpret_cast<const f32x4*>(p1 + y * Win + sx);  \
        }                                                                \
    }

    // ---- hoisted x-interp params: 3 q-phases (q=(16k+tid)%24 has period 3 in k) ----
    int   x0r[3][4];
    float wxr[3][4];
    {
        int q0 = tid % 24;
        int q1 = q0 + 16; if (q1 >= 24) q1 -= 24;
        int q2 = q0 + 8;  if (q2 >= 24) q2 -= 24;
        int qs[3] = {q0, q1, q2};
#pragma unroll
        for (int p = 0; p < 3; ++p) {
#pragma unroll
            for (int i = 0; i < 4; ++i) {
                int   xo = qs[p] * 4 + i;
                float fx = (float)(xo * (Win - 1)) * (1.0f / (float)(Wo - 1));
                int   x0 = (int)fx;
                x0r[p][i] = x0;
                wxr[p][i] = fx - (float)x0;
            }
        }
    }

    ISSUE_LOADS(zo0)                          // prologue: plane 0 loads in flight

    for (int j = 0; j < PPB; ++j) {
        const int zo = zo0 + j;
        float fz  = (float)(zo * (Din - 1)) * (1.0f / (float)(Do - 1));
        float wz1 = fz - (float)(int)fz;
        float wz0 = 1.0f - wz1;

        // ---- STAGE: regs -> G (32 exps/thread) ----
#pragma unroll
        for (int k = 0; k < 4; ++k) {
            int y = sy + k * 16;
            f32x4 g;
#pragma unroll
            for (int i = 0; i < 4; ++i)
                g[i] = wz0 * __builtin_amdgcn_exp2f(ra[k][i] * HALF_LOG2E)
                     + wz1 * __builtin_amdgcn_exp2f(rb[k][i] * HALF_LOG2E);
            *reinterpret_cast<f32x4*>(&G[y][sx]) = g;
        }
        __syncthreads();

        if (j + 1 < PPB) ISSUE_LOADS(zo + 1)  // in flight under phases 2-3 (~4K cycles)

        const size_t obase = ((size_t)nc * Do + zo) * (size_t)(Ho * Wo);

#pragma unroll
        for (int h = 0; h < 2; ++h) {
            // ---- phase 2: F2 for this half (float4 DS granularity) ----
            {
#pragma unroll
                for (int jj = 0; jj < 3; ++jj) {
                    int   r   = sy + 16 * jj;                // 0..47
                    int   yo  = h * HROWS + r;
                    float fy  = (float)(yo * (Hin - 1)) * (1.0f / (float)(Ho - 1));
                    int   y0  = (int)fy;
                    float wy1 = fy - (float)y0;
                    int   y1  = min(y0 + 1, Hin - 1);
                    f32x4 g0 = *reinterpret_cast<const f32x4*>(&G[y0][sx]);
                    f32x4 g1 = *reinterpret_cast<const f32x4*>(&G[y1][sx]);
                    f32x4 f  = g0 + wy1 * (g1 - g0);
                    *reinterpret_cast<f32x4*>(&F2[r][sx]) = f;
                    if (sx == 60) F2[r][64] = f.w;           // edge dup: x0+1 always valid
                }
            }
            __syncthreads();

            // ---- phase 3: 1152 quads, hoisted x-params, contiguous dwordx4 stores ----
            float* __restrict__ ob = out + obase + (size_t)h * (HROWS * Wo);
#pragma unroll
            for (int k = 0; k < 5; ++k) {
                int c = k * BLOCK + tid;
                if (c < QUADS) {                             // k==4: tid<128 tail
                    int row = (c * 2731) >> 16;              // c/24, exact for c < 2304
                    const float* __restrict__ rp = &F2[row][0];
                    f32x4 o;
#pragma unroll
                    for (int i = 0; i < 4; ++i) {
                        int   x0  = x0r[k % 3][i];
                        float wx1 = wxr[k % 3][i];
                        float F0 = rp[x0], F1 = rp[x0 + 1];  // adjacent -> ds_read2_b32
                        o[i] = TWO_LN2 * __log2f(F0 + wx1 * (F1 - F0));
                    }
                    *reinterpret_cast<f32x4*>(ob + (size_t)c * 4) = o;
                }
            }
            __syncthreads();   // h=0: WAR on F2; h=1: protects G before next STAGE
        }
    }
#undef ISSUE_LOADS
}

extern "C" void kernel_launch(void* const* d_in, const int* in_sizes, int n_in,
                              void* d_out, int out_size, void* d_ws, size_t ws_size,
                              hipStream_t stream) {
    const float* x = (const float*)d_in[0];
    float* out = (float*)d_out;
    resample3d_var_kernel<<<NBLOCKS, BLOCK, 0, stream>>>(x, out);
}

// Round 11
// 137.496 us; speedup vs baseline: 1.0903x; 1.0903x over previous
//
#include <hip/hip_runtime.h>

// x:(8,32,32,64,64) f32 -> out:(8,32,48,96,96) f32
// variance=1: out = 2*log( trilinear( exp(x/2) ) ), identity grid, align_corners=True.
//
// R9 structure EXACTLY, single change: output stores are nontemporal (streaming).
// Rationale: 442 MB/replay of write traffic streams through L3 and evicts the
// 134 MB input between replays (FETCH_SIZE ~96 MB observed). nt stores keep the
// input L3-resident and free L2 for z-plane reuse.
constexpr int N = 8, C = 32, Din = 32, Hin = 64, Win = 64;
constexpr int Do = 48, Ho = 96, Wo = 96;

constexpr int BLOCK   = 256;
constexpr int NBLOCKS = N * C * Do;          // 12288: one per (nc, zo)
constexpr int GPAD    = 68;                  // rows 16B-aligned, banks shift 4/row
constexpr int F2PAD   = 68;
constexpr int HROWS   = 48;                  // output rows per half
constexpr int QUADS   = HROWS * (Wo / 4);    // 1152 per half

typedef float f32x4 __attribute__((ext_vector_type(4)));

__global__ __launch_bounds__(BLOCK, 5)
void resample3d_var_kernel(const float* __restrict__ in, float* __restrict__ out) {
    __shared__ float G[Hin][GPAD];           // 17408 B
    __shared__ float F2[HROWS][F2PAD];       // 13056 B

    const int tid = threadIdx.x;
    const int bid = blockIdx.x;
    const int zo  = bid % Do;
    const int nc  = bid / Do;

    // z weights (block-uniform)
    float fz  = (float)(zo * (Din - 1)) * (1.0f / (float)(Do - 1));
    int   z0  = (int)fz;
    float wz1 = fz - (float)z0;
    int   z1  = min(z0 + 1, Din - 1);
    float wz0 = 1.0f - wz1;

    const float* __restrict__ p0 = in + ((size_t)nc * Din + z0) * (Hin * Win);
    const float* __restrict__ p1 = in + ((size_t)nc * Din + z1) * (Hin * Win);

    constexpr float HALF_LOG2E = 0.7213475204444817f;   // exp(x/2)  = exp2(x*K)
    constexpr float TWO_LN2    = 1.3862943611198906f;   // 2*logf(v) = TWO_LN2*log2f(v)

    // ---- Phase 1: stage G (4096 floats = 1024 float4 chunks, exactly 4/thread) ----
    {
        const int sy = tid >> 4;             // 0..15
        const int sx = (tid & 15) << 2;      // 0,4,...,60
#pragma unroll
        for (int k = 0; k < 4; ++k) {
            int y = sy + k * 16;
            const float4 a = *reinterpret_cast<const float4*>(p0 + y * Win + sx);
            const float4 b = *reinterpret_cast<const float4*>(p1 + y * Win + sx);
            float4 g;
            g.x = wz0 * __builtin_amdgcn_exp2f(a.x * HALF_LOG2E) + wz1 * __builtin_amdgcn_exp2f(b.x * HALF_LOG2E);
            g.y = wz0 * __builtin_amdgcn_exp2f(a.y * HALF_LOG2E) + wz1 * __builtin_amdgcn_exp2f(b.y * HALF_LOG2E);
            g.z = wz0 * __builtin_amdgcn_exp2f(a.z * HALF_LOG2E) + wz1 * __builtin_amdgcn_exp2f(b.z * HALF_LOG2E);
            g.w = wz0 * __builtin_amdgcn_exp2f(a.w * HALF_LOG2E) + wz1 * __builtin_amdgcn_exp2f(b.w * HALF_LOG2E);
            *reinterpret_cast<float4*>(&G[y][sx]) = g;
        }
    }
    __syncthreads();

    // ---- Hoisted x-interp params: 3 q-phases (q = (16k+tid)%24, period 3 in k) ----
    int   x0r[3][4];
    float wxr[3][4];
    {
        int q0 = tid % 24;
        int q1 = q0 + 16; if (q1 >= 24) q1 -= 24;
        int q2 = q0 + 8;  if (q2 >= 24) q2 -= 24;
        int qs[3] = {q0, q1, q2};
#pragma unroll
        for (int p = 0; p < 3; ++p) {
#pragma unroll
            for (int i = 0; i < 4; ++i) {
                int   xo = qs[p] * 4 + i;
                float fx = (float)(xo * (Win - 1)) * (1.0f / (float)(Wo - 1));
                int   x0 = (int)fx;
                x0r[p][i] = x0;
                wxr[p][i] = fx - (float)x0;
            }
        }
    }

    const size_t obase = ((size_t)nc * Do + zo) * (size_t)(Ho * Wo);

#pragma unroll
    for (int h = 0; h < 2; ++h) {
        // ---- Phase 2: F2 for this half (48 rows x 64), float4 granularity ----
        {
            const int xc = (tid & 15) << 2;  // 0,4,...,60
            const int r0 = tid >> 4;         // 0..15
#pragma unroll
            for (int j = 0; j < 3; ++j) {
                int   r   = r0 + 16 * j;                 // 0..47
                int   yo  = h * HROWS + r;
                float fy  = (float)(yo * (Hin - 1)) * (1.0f / (float)(Ho - 1));
                int   y0  = (int)fy;
                float wy1 = fy - (float)y0;
                int   y1  = min(y0 + 1, Hin - 1);
                f32x4 g0 = *reinterpret_cast<const f32x4*>(&G[y0][xc]);
                f32x4 g1 = *reinterpret_cast<const f32x4*>(&G[y1][xc]);
                f32x4 f  = g0 + wy1 * (g1 - g0);
                *reinterpret_cast<f32x4*>(&F2[r][xc]) = f;
                if (xc == 60) F2[r][64] = f.w;           // edge dup: x1=x0+1 always valid
            }
        }
        __syncthreads();

        // ---- Phase 3: 1152 quads, hoisted x-params, contiguous NT dwordx4 stores ----
        float* __restrict__ ob = out + obase + (size_t)h * (HROWS * Wo);
#pragma unroll
        for (int k = 0; k < 5; ++k) {
            int c = k * BLOCK + tid;
            if (c < QUADS) {                             // k==4: tid<128 tail
                int row = (c * 2731) >> 16;              // c/24, exact for c < 2304
                const float* __restrict__ rp = &F2[row][0];
                f32x4 o;
#pragma unroll
                for (int i = 0; i < 4; ++i) {
                    int   x0  = x0r[k % 3][i];
                    float wx1 = wxr[k % 3][i];
                    float F0 = rp[x0], F1 = rp[x0 + 1];  // adjacent -> ds_read2_b32
                    o[i] = TWO_LN2 * __log2f(F0 + wx1 * (F1 - F0));
                }
                __builtin_nontemporal_store(o, reinterpret_cast<f32x4*>(ob + (size_t)c * 4));
            }
        }
        if (h == 0) __syncthreads();                     // WAR on F2
    }
}

extern "C" void kernel_launch(void* const* d_in, const int* in_sizes, int n_in,
                              void* d_out, int out_size, void* d_ws, size_t ws_size,
                              hipStream_t stream) {
    const float* x = (const float*)d_in[0];
    float* out = (float*)d_out;
    resample3d_var_kernel<<<NBLOCKS, BLOCK, 0, stream>>>(x, out);
}

// Round 12
// 124.152 us; speedup vs baseline: 1.2075x; 1.1075x over previous
//
#include <hip/hip_runtime.h>

// x:(8,32,32,64,64) f32 -> out:(8,32,48,96,96) f32
// variance=1: out = 2*log( trilinear( exp(x/2) ) ), identity grid, align_corners=True.
//
// R9 3-phase structure; this rev: packed-f32 math (v_pk_fma_f32) in phases 1/3,
// hoisted byte offsets for the phase-3 ds_read2 pairs.
constexpr int N = 8, C = 32, Din = 32, Hin = 64, Win = 64;
constexpr int Do = 48, Ho = 96, Wo = 96;

constexpr int BLOCK   = 256;
constexpr int NBLOCKS = N * C * Do;          // 12288: one per (nc, zo)
constexpr int GPAD    = 68;                  // rows 16B-aligned, banks shift 4/row
constexpr int F2PAD   = 68;
constexpr int HROWS   = 48;                  // output rows per half
constexpr int QUADS   = HROWS * (Wo / 4);    // 1152 per half

typedef float f32x4 __attribute__((ext_vector_type(4)));

__global__ __launch_bounds__(BLOCK, 5)
void resample3d_var_kernel(const float* __restrict__ in, float* __restrict__ out) {
    __shared__ float G[Hin][GPAD];           // 17408 B
    __shared__ float F2[HROWS][F2PAD];       // 13056 B

    const int tid = threadIdx.x;
    const int bid = blockIdx.x;
    const int zo  = bid % Do;
    const int nc  = bid / Do;

    // z weights (block-uniform)
    float fz  = (float)(zo * (Din - 1)) * (1.0f / (float)(Do - 1));
    int   z0  = (int)fz;
    float wz1 = fz - (float)z0;
    int   z1  = min(z0 + 1, Din - 1);
    float wz0 = 1.0f - wz1;

    const float* __restrict__ p0 = in + ((size_t)nc * Din + z0) * (Hin * Win);
    const float* __restrict__ p1 = in + ((size_t)nc * Din + z1) * (Hin * Win);

    constexpr float HALF_LOG2E = 0.7213475204444817f;   // exp(x/2)  = exp2(x*K)
    constexpr float TWO_LN2    = 1.3862943611198906f;   // 2*logf(v) = TWO_LN2*log2f(v)

    // ---- Phase 1: stage G (1024 float4 chunks, 4/thread; packed f32 math) ----
    {
        const int sy = tid >> 4;             // 0..15
        const int sx = (tid & 15) << 2;      // 0,4,...,60
#pragma unroll
        for (int k = 0; k < 4; ++k) {
            int y = sy + k * 16;
            f32x4 a = *reinterpret_cast<const f32x4*>(p0 + y * Win + sx);
            f32x4 b = *reinterpret_cast<const f32x4*>(p1 + y * Win + sx);
            f32x4 as = a * HALF_LOG2E;       // v_pk_mul_f32 x2
            f32x4 bs = b * HALF_LOG2E;
            f32x4 e0, e1;
#pragma unroll
            for (int i = 0; i < 4; ++i) {
                e0[i] = __builtin_amdgcn_exp2f(as[i]);
                e1[i] = __builtin_amdgcn_exp2f(bs[i]);
            }
            f32x4 g = e0 * wz0 + e1 * wz1;   // pk_mul + pk_fma x2
            *reinterpret_cast<f32x4*>(&G[y][sx]) = g;
        }
    }
    __syncthreads();

    // ---- Hoisted x-interp params: 3 q-phases (q = (16k+tid)%24, period 3 in k) ----
    int   x0r[3][4];                         // element offsets into an F2 row
    f32x4 wxv[3];                            // packed x-weights
    {
        int q0 = tid % 24;
        int q1 = q0 + 16; if (q1 >= 24) q1 -= 24;
        int q2 = q0 + 8;  if (q2 >= 24) q2 -= 24;
        int qs[3] = {q0, q1, q2};
#pragma unroll
        for (int p = 0; p < 3; ++p) {
#pragma unroll
            for (int i = 0; i < 4; ++i) {
                int   xo = qs[p] * 4 + i;
                float fx = (float)(xo * (Win - 1)) * (1.0f / (float)(Wo - 1));
                int   x0 = (int)fx;
                x0r[p][i] = x0;
                wxv[p][i] = fx - (float)x0;
            }
        }
    }

    const size_t obase = ((size_t)nc * Do + zo) * (size_t)(Ho * Wo);

#pragma unroll
    for (int h = 0; h < 2; ++h) {
        // ---- Phase 2: F2 for this half (48 rows x 64), float4 granularity ----
        {
            const int xc = (tid & 15) << 2;  // 0,4,...,60
            const int r0 = tid >> 4;         // 0..15
#pragma unroll
            for (int j = 0; j < 3; ++j) {
                int   r   = r0 + 16 * j;                 // 0..47
                int   yo  = h * HROWS + r;
                float fy  = (float)(yo * (Hin - 1)) * (1.0f / (float)(Ho - 1));
                int   y0  = (int)fy;
                float wy1 = fy - (float)y0;
                int   y1  = min(y0 + 1, Hin - 1);
                f32x4 g0 = *reinterpret_cast<const f32x4*>(&G[y0][xc]);
                f32x4 g1 = *reinterpret_cast<const f32x4*>(&G[y1][xc]);
                f32x4 f  = g0 + wy1 * (g1 - g0);         // pk_add + pk_fma
                *reinterpret_cast<f32x4*>(&F2[r][xc]) = f;
                if (xc == 60) F2[r][64] = f.w;           // edge dup: x1=x0+1 always valid
            }
        }
        __syncthreads();

        // ---- Phase 3: 1152 quads; vector lerp (packed), scalar logs, dwordx4 stores ----
        float* __restrict__ ob = out + obase + (size_t)h * (HROWS * Wo);
#pragma unroll
        for (int k = 0; k < 5; ++k) {
            int c = k * BLOCK + tid;
            if (c < QUADS) {                             // k==4: tid<128 tail
                int row = (c * 2731) >> 16;              // c/24, exact for c < 2304
                const float* __restrict__ rp = &F2[row][0];
                const int* xr = x0r[k % 3];
                f32x4 F0, F1;
#pragma unroll
                for (int i = 0; i < 4; ++i) {            // 4x ds_read2_b32 (adjacent pair)
                    F0[i] = rp[xr[i]];
                    F1[i] = rp[xr[i] + 1];
                }
                f32x4 v = F0 + wxv[k % 3] * (F1 - F0);   // pk_add + pk_fma x2
                f32x4 l;
#pragma unroll
                for (int i = 0; i < 4; ++i) l[i] = __log2f(v[i]);
                f32x4 o = l * TWO_LN2;                   // pk_mul x2
                *reinterpret_cast<f32x4*>(ob + (size_t)c * 4) = o;
            }
        }
        if (h == 0) __syncthreads();                     // WAR on F2
    }
}

extern "C" void kernel_launch(void* const* d_in, const int* in_sizes, int n_in,
                              void* d_out, int out_size, void* d_ws, size_t ws_size,
                              hipStream_t stream) {
    const float* x = (const float*)d_in[0];
    float* out = (float*)d_out;
    resample3d_var_kernel<<<NBLOCKS, BLOCK, 0, stream>>>(x, out);
}